// Round 5
// baseline (137.660 us; speedup 1.0000x reference)
//
#include <hip/hip_runtime.h>
#include <math.h>

typedef _Float16 h2_t __attribute__((ext_vector_type(2)));
typedef _Float16 h4_t __attribute__((ext_vector_type(4)));
typedef _Float16 h8_t __attribute__((ext_vector_type(8)));

#define NP 32
#define KC 31
#define HH 512
#define WW 512
#define BB 4
#define CC 3

#define TXO 64        // 64-wide tile, 512-thread block
#define TYO 32
#define NT 512        // threads per block
#define TROWS 62      // 32 outputs + 15 + 15 halo
#define TWORDS 48     // row stride in h2 words
#define TILEW (TROWS * TWORDS)   // 2976 h2 words per channel tile
#define WSTR 36       // weight table plane stride in h2 words

// HARD CONSTRAINTS (measured R0-R4):
//  - grid z = BB; >128 VGPRs unobtainable -> 4 outputs/thread (wj[64]);
//    insert-style unpack; fdot2 == pk_fma rate -> dy-loop is FINAL.
//  - NOTHING may be live across the wj-resident compute loop (R1/R2/R3 all
//    spilled: WRITE 15/52/92 MB). global_load_lds also loses L2 halo reuse.
//  - Staging values may NOT coexist with the f64 wtab-build temps (R1 spill).
// R4 (85us kernel, VALU 60%, WRITE 12.3MB clean): 3 per-channel stage->drain->
// barrier phases = ~34us idle. THIS ROUND: 3 private LDS tiles (40.3KB, still
// 2 blocks/CU) staged back-to-back AFTER the wtab build (f64 temps dead, with
// a sched_barrier fence so loads can't hoist across), ONE barrier, then three
// barrier-free compute passes. Staging loop body is R4-verbatim (proven
// no-spill transient), channel loop unroll 1 caps live floats at ~12.

__device__ __forceinline__ double plane_of(int i) {
    const double stepd = 50.0 / 31.0;
    return (i < 31) ? (double)i * stepd : 50.0;
}

__launch_bounds__(512, 2)
__global__ void defocus_kernel(const float* __restrict__ img,
                               const float* __restrict__ coc,
                               float* __restrict__ out) {
    const int tx = threadIdx.x;            // 0..15
    const int ty = threadIdx.y;            // 0..31
    const int tid = ty * 16 + tx;
    const int tilex = blockIdx.x * TXO;
    const int tiley = blockIdx.y * TYO;
    const int b = blockIdx.z;

    __shared__ __align__(16) h2_t wtab[NP * WSTR];   //  4608 B
    __shared__ __align__(16) h2_t tile[3 * TILEW];   // 35712 B (total 40320)

    const int yo = tiley + ty;
    const int xo = tilex + tx * 4;

    // ---- (1) coc load first; its latency hides under the wtab build
    const float4 cv = *(const float4*)&coc[((size_t)b * HH + yo) * WW + xo];

    // ---- (2) in-block wtab build (bit-identical across R1-R4). All f64/expf
    //          temps die at the end of this block -- BEFORE staging begins.
    {
        const int t = tid & 31;               // padded tap position 0..31
        #pragma unroll
        for (int pass = 0; pass < 2; ++pass) {
            const int p = (tid >> 5) + 16 * pass;   // plane 0..31
            const double stepd = 50.0 / 31.0;
            double cocp = (p < 31) ? (double)p * stepd : 50.0;  // numpy linspace
            float gt;
            if (cocp < 0.5) {
                gt = (t == 15) ? 1.f : 0.f;   // identity plane (plane 0 only)
            } else {
                double sigma = cocp / 2.355;
                int k = (int)(2.0 * cocp + 1.0);   // trunc, matches python int()
                if ((k & 1) == 0) k += 1;
                if (k > KC) k = KC;
                int h = k / 2;
                int d = t - 15;
                float denom = (float)(2.0 * sigma * sigma);
                float v = (d >= -h && d <= h && t < KC) ? expf(-(float)(d * d) / denom) : 0.f;
                float s = v;
                #pragma unroll
                for (int off = 1; off < 32; off <<= 1) s += __shfl_xor(s, off, 32);
                gt = v / s;
            }
            const int m = t & 15;
            const int s0 = (t < 16) ? (2 * m) : ((2 * m - 1 < 0) ? 0 : 2 * m - 1);
            const int s1 = (t < 16) ? (2 * m + 1) : (2 * m);
            float w0 = __shfl(gt, s0, 32);
            float w1 = __shfl(gt, s1, 32);
            if (t >= 16 && (2 * m - 1) < 0) w0 = 0.f;   // g[-1] = 0
            h2_t w; w.x = (_Float16)w0; w.y = (_Float16)w1;
            wtab[p * WSTR + t] = w;
            if (t < WSTR - 32) {
                h2_t z; z.x = (_Float16)0.f; z.y = (_Float16)0.f;
                wtab[p * WSTR + 32 + t] = z;
            }
        }
    }

    // ---- (3) per-pixel bin index, exact double-precision boundary semantics
    const float cocf[4] = {cv.x, cv.y, cv.z, cv.w};
    int idx[4];
    #pragma unroll
    for (int j = 0; j < 4; ++j) {
        const double stepd = 50.0 / 31.0;
        double cd = (double)cocf[j];
        int i0 = (int)floor(cd / stepd + 0.5);
        i0 = min(max(i0, 0), 31);
        if (i0 > 0 && cd <= 0.5 * (plane_of(i0 - 1) + plane_of(i0))) {
            i0 -= 1;
        } else if (i0 < 31 && cd > 0.5 * (plane_of(i0) + plane_of(i0 + 1))) {
            i0 += 1;
        }
        idx[j] = i0;
    }

    // Fence: forbid the scheduler from hoisting staging loads up across the
    // f64-heavy region above (that exact hoist was R1's spill).
    __builtin_amdgcn_sched_barrier(0);

    // ---- (4) stage ALL THREE channels into private tiles, back-to-back.
    //          Body is R4-verbatim (transient v0/v1 only); unroll 1 keeps the
    //          live set per channel at ~12 floats. No barriers in between.
    #pragma unroll 1
    for (int c = 0; c < CC; ++c) {
        const float* src = img + (size_t)(b * CC + c) * HH * WW;
        h2_t* tdst = tile + c * TILEW;
        for (int f = tid; f < TILEW; f += NT) {
            int r = f / TWORDS;
            int w = f - r * TWORDS;
            int gy = tiley - 15 + r;
            int gx = tilex - 15 + 2 * w;
            float v0 = 0.f, v1 = 0.f;
            if ((unsigned)gy < (unsigned)HH) {
                if ((unsigned)gx < (unsigned)WW) v0 = src[gy * WW + gx];
                if ((unsigned)(gx + 1) < (unsigned)WW) v1 = src[gy * WW + gx + 1];
            }
            h2_t pv; pv.x = (_Float16)v0; pv.y = (_Float16)v1;
            tdst[f] = pv;
        }
    }

    __syncthreads();   // the ONLY barrier: wtab + all three tiles staged

    // ---- (5) gather this thread's 4 weight rows into registers
    // even local col (j=0,2): phase A; odd (j=1,3): phase B (pre-shifted one tap)
    h2_t wj[4][16];
    #pragma unroll
    for (int j = 0; j < 4; ++j) {
        const h2_t* wp = &wtab[idx[j] * WSTR + (j & 1) * 16];
        #pragma unroll
        for (int m = 0; m < 4; ++m) {
            h8_t v = *(const h8_t*)(wp + 4 * m);   // 16B aligned: WSTR%4==0
            #pragma unroll
            for (int q = 0; q < 4; ++q) {
                h2_t t2; t2.x = v[2 * q]; t2.y = v[2 * q + 1];
                wj[j][4 * m + q] = t2;
            }
        }
    }

    // ---- (6) three compute passes, zero further barriers (private tiles)
    #pragma unroll 1
    for (int c = 0; c < CC; ++c) {
        float acc0 = 0.f, acc1 = 0.f, acc2 = 0.f, acc3 = 0.f;
        const h2_t* rowbase = &tile[c * TILEW + ty * TWORDS + 2 * tx];
        #pragma unroll
        for (int dy = 0; dy < KC; ++dy) {
            const h2_t* rp = rowbase + dy * TWORDS;
            h2_t rw[18];
            #pragma unroll
            for (int m = 0; m < 9; ++m) {
                h4_t q = *(const h4_t*)(rp + 2 * m);   // ds_read_b64, conflict-free
                h2_t lo; lo.x = q[0]; lo.y = q[1];
                h2_t hi; hi.x = q[2]; hi.y = q[3];
                rw[2 * m]     = lo;
                rw[2 * m + 1] = hi;
            }
            float rs0 = 0.f, rs1 = 0.f, rs2 = 0.f, rs3 = 0.f;
            #pragma unroll
            for (int m = 0; m < 16; ++m) {
                rs0 = __builtin_amdgcn_fdot2(wj[0][m], rw[m],     rs0, false);
                rs1 = __builtin_amdgcn_fdot2(wj[1][m], rw[m],     rs1, false);
                rs2 = __builtin_amdgcn_fdot2(wj[2][m], rw[m + 1], rs2, false);
                rs3 = __builtin_amdgcn_fdot2(wj[3][m], rw[m + 1], rs3, false);
            }
            // column taps g[dy] from the same registers (dy unrolled -> static)
            float cw0, cw1, cw2, cw3;
            if ((dy & 1) == 0) {
                cw0 = (float)wj[0][dy >> 1].x;           // A: lo = g[dy]
                cw2 = (float)wj[2][dy >> 1].x;
                cw1 = (float)wj[1][dy >> 1].y;           // B: hi = g[dy]
                cw3 = (float)wj[3][dy >> 1].y;
            } else {
                cw0 = (float)wj[0][dy >> 1].y;           // A: hi = g[dy]
                cw2 = (float)wj[2][dy >> 1].y;
                cw1 = (float)wj[1][(dy + 1) >> 1].x;     // B: lo of next = g[dy]
                cw3 = (float)wj[3][(dy + 1) >> 1].x;
            }
            acc0 += cw0 * rs0;
            acc1 += cw1 * rs1;
            acc2 += cw2 * rs2;
            acc3 += cw3 * rs3;
        }

        *(float4*)&out[((size_t)(b * CC + c) * HH + yo) * WW + xo] =
            make_float4(acc0, acc1, acc2, acc3);
    }
}

extern "C" void kernel_launch(void* const* d_in, const int* in_sizes, int n_in,
                              void* d_out, int out_size, void* d_ws, size_t ws_size,
                              hipStream_t stream) {
    const float* sharp = (const float*)d_in[0];
    const float* cocm  = (const float*)d_in[1];
    float* out = (float*)d_out;

    dim3 grid(WW / TXO, HH / TYO, BB);
    dim3 block(16, 32, 1);
    defocus_kernel<<<grid, block, 0, stream>>>(sharp, cocm, out);
}

// Round 6
// 127.745 us; speedup vs baseline: 1.0776x; 1.0776x over previous
//
#include <hip/hip_runtime.h>
#include <math.h>

typedef _Float16 h2_t __attribute__((ext_vector_type(2)));
typedef _Float16 h4_t __attribute__((ext_vector_type(4)));
typedef _Float16 h8_t __attribute__((ext_vector_type(8)));

#define NP 32
#define KC 31
#define HH 512
#define WW 512
#define BB 4
#define CC 3

#define TXO 64        // 64-wide tile, 512-thread block
#define TYO 32
#define NT 512        // threads per block
#define TROWS 62      // 32 outputs + 15 + 15 halo
#define TWORDS 48     // row stride in h2 words
#define TILEW (TROWS * TWORDS)   // 2976 h2 words per channel tile
#define WSTR 36       // weight table plane stride in h2 words

// HARD CONSTRAINTS (measured R0-R5):
//  - grid z = BB; >128 VGPRs unobtainable -> 4 outputs/thread (wj[64]);
//    insert-style unpack; fdot2 == pk_fma rate (both HALF-rate, 4cyc).
//  - NOTHING may be live across the wj-resident compute loop (R1/R2/R3
//    spilled: WRITE 15/52/92 MB). global_load_lds loses L2 halo reuse.
//  - Barrier structure is NOT the bottleneck (R5: 7->2 barriers = 0 gain).
//    Kernel is fdot2-ISSUE-bound: 51us of 85us is VALU issue, ~2x the 2-cyc
//    model -> fdot2 is 4-cyc. Only reducing fdot2 COUNT helps.
// THIS ROUND: Gaussian symmetry g[15-d]==g[15+d] (exact: same expf input,
// shared normalization) + linearity of the horizontal dot ->
//   sum_dy g[dy]*hdot(row_dy) = g[15]*hdot(row_15)
//                             + sum_{d=1..15} g[15-d]*hdot(row_{15-d}+row_{15+d})
// Rows folded pairwise in f16 (v_pk_add_f16, full-rate-or-equal), horizontal
// dot runs ONCE per pair: fdot2/channel 1984 -> 1024 (-48%). LDS b64 reads
// unchanged (279). Extra rounding from the f16 fold <= ~5e-4 (weights sum 1).

__device__ __forceinline__ double plane_of(int i) {
    const double stepd = 50.0 / 31.0;
    return (i < 31) ? (double)i * stepd : 50.0;
}

__launch_bounds__(512, 2)
__global__ void defocus_kernel(const float* __restrict__ img,
                               const float* __restrict__ coc,
                               float* __restrict__ out) {
    const int tx = threadIdx.x;            // 0..15
    const int ty = threadIdx.y;            // 0..31
    const int tid = ty * 16 + tx;
    const int tilex = blockIdx.x * TXO;
    const int tiley = blockIdx.y * TYO;
    const int b = blockIdx.z;

    __shared__ __align__(16) h2_t wtab[NP * WSTR];   //  4608 B
    __shared__ __align__(16) h2_t tile[3 * TILEW];   // 35712 B (total 40320)

    const int yo = tiley + ty;
    const int xo = tilex + tx * 4;

    // ---- (1) coc load first; its latency hides under the wtab build
    const float4 cv = *(const float4*)&coc[((size_t)b * HH + yo) * WW + xo];

    // ---- (2) in-block wtab build (bit-identical across R1-R5). All f64/expf
    //          temps die at the end of this block -- BEFORE staging begins.
    {
        const int t = tid & 31;               // padded tap position 0..31
        #pragma unroll
        for (int pass = 0; pass < 2; ++pass) {
            const int p = (tid >> 5) + 16 * pass;   // plane 0..31
            const double stepd = 50.0 / 31.0;
            double cocp = (p < 31) ? (double)p * stepd : 50.0;  // numpy linspace
            float gt;
            if (cocp < 0.5) {
                gt = (t == 15) ? 1.f : 0.f;   // identity plane (plane 0 only)
            } else {
                double sigma = cocp / 2.355;
                int k = (int)(2.0 * cocp + 1.0);   // trunc, matches python int()
                if ((k & 1) == 0) k += 1;
                if (k > KC) k = KC;
                int h = k / 2;
                int d = t - 15;
                float denom = (float)(2.0 * sigma * sigma);
                float v = (d >= -h && d <= h && t < KC) ? expf(-(float)(d * d) / denom) : 0.f;
                float s = v;
                #pragma unroll
                for (int off = 1; off < 32; off <<= 1) s += __shfl_xor(s, off, 32);
                gt = v / s;
            }
            const int m = t & 15;
            const int s0 = (t < 16) ? (2 * m) : ((2 * m - 1 < 0) ? 0 : 2 * m - 1);
            const int s1 = (t < 16) ? (2 * m + 1) : (2 * m);
            float w0 = __shfl(gt, s0, 32);
            float w1 = __shfl(gt, s1, 32);
            if (t >= 16 && (2 * m - 1) < 0) w0 = 0.f;   // g[-1] = 0
            h2_t w; w.x = (_Float16)w0; w.y = (_Float16)w1;
            wtab[p * WSTR + t] = w;
            if (t < WSTR - 32) {
                h2_t z; z.x = (_Float16)0.f; z.y = (_Float16)0.f;
                wtab[p * WSTR + 32 + t] = z;
            }
        }
    }

    // ---- (3) per-pixel bin index, exact double-precision boundary semantics
    const float cocf[4] = {cv.x, cv.y, cv.z, cv.w};
    int idx[4];
    #pragma unroll
    for (int j = 0; j < 4; ++j) {
        const double stepd = 50.0 / 31.0;
        double cd = (double)cocf[j];
        int i0 = (int)floor(cd / stepd + 0.5);
        i0 = min(max(i0, 0), 31);
        if (i0 > 0 && cd <= 0.5 * (plane_of(i0 - 1) + plane_of(i0))) {
            i0 -= 1;
        } else if (i0 < 31 && cd > 0.5 * (plane_of(i0) + plane_of(i0 + 1))) {
            i0 += 1;
        }
        idx[j] = i0;
    }

    // Fence: forbid hoisting staging loads up across the f64 region (R1 spill).
    __builtin_amdgcn_sched_barrier(0);

    // ---- (4) stage ALL THREE channels into private tiles, back-to-back.
    #pragma unroll 1
    for (int c = 0; c < CC; ++c) {
        const float* src = img + (size_t)(b * CC + c) * HH * WW;
        h2_t* tdst = tile + c * TILEW;
        for (int f = tid; f < TILEW; f += NT) {
            int r = f / TWORDS;
            int w = f - r * TWORDS;
            int gy = tiley - 15 + r;
            int gx = tilex - 15 + 2 * w;
            float v0 = 0.f, v1 = 0.f;
            if ((unsigned)gy < (unsigned)HH) {
                if ((unsigned)gx < (unsigned)WW) v0 = src[gy * WW + gx];
                if ((unsigned)(gx + 1) < (unsigned)WW) v1 = src[gy * WW + gx + 1];
            }
            h2_t pv; pv.x = (_Float16)v0; pv.y = (_Float16)v1;
            tdst[f] = pv;
        }
    }

    __syncthreads();   // the ONLY barrier: wtab + all three tiles staged

    // ---- (5) gather this thread's 4 weight rows into registers
    // even local col (j=0,2): phase A; odd (j=1,3): phase B (pre-shifted one tap)
    h2_t wj[4][16];
    #pragma unroll
    for (int j = 0; j < 4; ++j) {
        const h2_t* wp = &wtab[idx[j] * WSTR + (j & 1) * 16];
        #pragma unroll
        for (int m = 0; m < 4; ++m) {
            h8_t v = *(const h8_t*)(wp + 4 * m);   // 16B aligned: WSTR%4==0
            #pragma unroll
            for (int q = 0; q < 4; ++q) {
                h2_t t2; t2.x = v[2 * q]; t2.y = v[2 * q + 1];
                wj[j][4 * m + q] = t2;
            }
        }
    }

// horizontal dot over 17 live words (rs0/1 use rw[0..15], rs2/3 use rw[1..16])
#define HDOT(RW, RS0, RS1, RS2, RS3)                                         \
    {                                                                        \
        _Pragma("unroll")                                                    \
        for (int m = 0; m < 16; ++m) {                                       \
            RS0 = __builtin_amdgcn_fdot2(wj[0][m], RW[m],     RS0, false);   \
            RS1 = __builtin_amdgcn_fdot2(wj[1][m], RW[m],     RS1, false);   \
            RS2 = __builtin_amdgcn_fdot2(wj[2][m], RW[m + 1], RS2, false);   \
            RS3 = __builtin_amdgcn_fdot2(wj[3][m], RW[m + 1], RS3, false);   \
        }                                                                    \
    }

// column-weight extraction for compile-time DY (verified phase mapping)
#define CWEXT(DY, CW0, CW1, CW2, CW3)                                        \
    {                                                                        \
        if (((DY) & 1) == 0) {                                               \
            CW0 = (float)wj[0][(DY) >> 1].x;                                 \
            CW2 = (float)wj[2][(DY) >> 1].x;                                 \
            CW1 = (float)wj[1][(DY) >> 1].y;                                 \
            CW3 = (float)wj[3][(DY) >> 1].y;                                 \
        } else {                                                             \
            CW0 = (float)wj[0][(DY) >> 1].y;                                 \
            CW2 = (float)wj[2][(DY) >> 1].y;                                 \
            CW1 = (float)wj[1][((DY) + 1) >> 1].x;                           \
            CW3 = (float)wj[3][((DY) + 1) >> 1].x;                           \
        }                                                                    \
    }

    // ---- (6) three compute passes; symmetric fold: 16 hdots instead of 31
    #pragma unroll 1
    for (int c = 0; c < CC; ++c) {
        float acc0 = 0.f, acc1 = 0.f, acc2 = 0.f, acc3 = 0.f;
        const h2_t* rowbase = &tile[c * TILEW + ty * TWORDS + 2 * tx];

        // center row (dy = 15), unfolded
        {
            const h2_t* rp = rowbase + 15 * TWORDS;
            h2_t rw[18];
            #pragma unroll
            for (int m = 0; m < 9; ++m) {
                h4_t q = *(const h4_t*)(rp + 2 * m);   // ds_read_b64
                h2_t lo; lo.x = q[0]; lo.y = q[1];
                h2_t hi; hi.x = q[2]; hi.y = q[3];
                rw[2 * m]     = lo;
                rw[2 * m + 1] = hi;
            }
            float rs0 = 0.f, rs1 = 0.f, rs2 = 0.f, rs3 = 0.f;
            HDOT(rw, rs0, rs1, rs2, rs3)
            float cw0, cw1, cw2, cw3;
            CWEXT(15, cw0, cw1, cw2, cw3)
            acc0 += cw0 * rs0;  acc1 += cw1 * rs1;
            acc2 += cw2 * rs2;  acc3 += cw3 * rs3;
        }

        // folded pairs: rows 15-d and 15+d share weight g[15-d] (exact symmetry)
        #pragma unroll
        for (int d = 1; d <= 15; ++d) {
            const h2_t* rpa = rowbase + (15 - d) * TWORDS;
            const h2_t* rpb = rowbase + (15 + d) * TWORDS;
            h2_t rw[18];
            #pragma unroll
            for (int m = 0; m < 9; ++m) {
                h4_t qa = *(const h4_t*)(rpa + 2 * m);   // ds_read_b64
                h4_t qb = *(const h4_t*)(rpb + 2 * m);   // ds_read_b64
                h4_t qs = qa + qb;                       // 2x v_pk_add_f16
                h2_t lo; lo.x = qs[0]; lo.y = qs[1];
                h2_t hi; hi.x = qs[2]; hi.y = qs[3];
                rw[2 * m]     = lo;
                rw[2 * m + 1] = hi;
            }
            float rs0 = 0.f, rs1 = 0.f, rs2 = 0.f, rs3 = 0.f;
            HDOT(rw, rs0, rs1, rs2, rs3)
            const int dy = 15 - d;                       // compile-time (unrolled)
            float cw0, cw1, cw2, cw3;
            CWEXT(dy, cw0, cw1, cw2, cw3)
            acc0 += cw0 * rs0;  acc1 += cw1 * rs1;
            acc2 += cw2 * rs2;  acc3 += cw3 * rs3;
        }

        *(float4*)&out[((size_t)(b * CC + c) * HH + yo) * WW + xo] =
            make_float4(acc0, acc1, acc2, acc3);
    }

#undef HDOT
#undef CWEXT
}

extern "C" void kernel_launch(void* const* d_in, const int* in_sizes, int n_in,
                              void* d_out, int out_size, void* d_ws, size_t ws_size,
                              hipStream_t stream) {
    const float* sharp = (const float*)d_in[0];
    const float* cocm  = (const float*)d_in[1];
    float* out = (float*)d_out;

    dim3 grid(WW / TXO, HH / TYO, BB);
    dim3 block(16, 32, 1);
    defocus_kernel<<<grid, block, 0, stream>>>(sharp, cocm, out);
}